// Round 1
// baseline (412.758 us; speedup 1.0000x reference)
//
#include <hip/hip_runtime.h>
#include <math.h>

#define BB 32
#define SS 128
#define DIN 16
#define HH 128
#define NBSH (BB*SS*HH)   // 524288

// ---------------- K1: three 1x1 convs (pointwise GEMM, K=16) ----------------
__global__ __launch_bounds__(128) void k_pointwise(
    const float* __restrict__ data,
    const float* __restrict__ w11, const float* __restrict__ b11,
    const float* __restrict__ w21, const float* __restrict__ b21,
    const float* __restrict__ w31, const float* __restrict__ b31,
    float* __restrict__ t1, float* __restrict__ t2, float* __restrict__ t3)
{
    int bs = blockIdx.x; int h = threadIdx.x;
    __shared__ float din[DIN];
    if (h < DIN) din[h] = data[bs*DIN + h];
    __syncthreads();
    float a1 = b11[h], a2 = b21[h], a3 = b31[h];
    #pragma unroll
    for (int c = 0; c < DIN; ++c){
        float d = din[c];
        a1 = fmaf(d, w11[h*DIN+c], a1);
        a2 = fmaf(d, w21[h*DIN+c], a2);
        a3 = fmaf(d, w31[h*DIN+c], a3);
    }
    int o = bs*HH + h;
    t1[o] = a1; t2[o] = a2; t3[o] = a3;
}

// ---------------- K2: dilated conv, SAME padding -----------------------------
template<int KW, int DIL, int TILE>
__global__ __launch_bounds__(128) void k_dilconv(
    const float* __restrict__ tin, const float* __restrict__ w,
    const float* __restrict__ bias, float* __restrict__ xout)
{
    constexpr int HALO = (KW/2)*DIL;
    constexpr int R = TILE + 2*HALO;
    int blk = blockIdx.x;
    int b  = blk / (SS/TILE);
    int s0 = (blk % (SS/TILE)) * TILE;
    int h = threadIdx.x;
    __shared__ float rows[R][HH];
    for (int r = 0; r < R; ++r){
        int sp = s0 - HALO + r;
        rows[r][h] = (sp >= 0 && sp < SS) ? tin[(b*SS+sp)*HH + h] : 0.f;
    }
    __syncthreads();
    float acc[TILE];
    float bv = bias[h];
    #pragma unroll
    for (int t = 0; t < TILE; ++t) acc[t] = bv;
    const float* wp = w + (size_t)h*HH*KW;
    for (int c = 0; c < HH; ++c){
        float wk[KW];
        #pragma unroll
        for (int k = 0; k < KW; ++k) wk[k] = wp[c*KW + k];
        #pragma unroll
        for (int t = 0; t < TILE; ++t){
            #pragma unroll
            for (int k = 0; k < KW; ++k)
                acc[t] = fmaf(rows[t + k*DIL][c], wk[k], acc[t]);
        }
    }
    for (int t = 0; t < TILE; ++t) xout[(b*SS+s0+t)*HH + h] = acc[t];
}

// ---------------- K3: concat + fuse GEMM (K=384) + relu ----------------------
template<int TILE>
__global__ __launch_bounds__(128) void k_fuse(
    const float* __restrict__ x1, const float* __restrict__ x2, const float* __restrict__ x3,
    const float* __restrict__ wf, const float* __restrict__ bf, float* __restrict__ x)
{
    int blk = blockIdx.x;
    int b  = blk / (SS/TILE);
    int s0 = (blk % (SS/TILE)) * TILE;
    int h = threadIdx.x;
    __shared__ float a1[TILE][HH], a2[TILE][HH], a3[TILE][HH];
    for (int t = 0; t < TILE; ++t){
        int r = (b*SS+s0+t)*HH + h;
        a1[t][h] = x1[r]; a2[t][h] = x2[r]; a3[t][h] = x3[r];
    }
    __syncthreads();
    float acc[TILE];
    float bv = bf[h];
    #pragma unroll
    for (int t = 0; t < TILE; ++t) acc[t] = bv;
    for (int c = 0; c < HH; ++c){
        float w1v = wf[c*HH + h];
        float w2v = wf[(HH+c)*HH + h];
        float w3v = wf[(2*HH+c)*HH + h];
        #pragma unroll
        for (int t = 0; t < TILE; ++t){
            acc[t] = fmaf(a1[t][c], w1v, acc[t]);
            acc[t] = fmaf(a2[t][c], w2v, acc[t]);
            acc[t] = fmaf(a3[t][c], w3v, acc[t]);
        }
    }
    for (int t = 0; t < TILE; ++t) x[(b*SS+s0+t)*HH + h] = fmaxf(acc[t], 0.f);
}

// ---------------- K4: hs (transposed) and hr(+b1) ----------------------------
template<int TILE>
__global__ __launch_bounds__(128) void k_hs_hr(
    const float* __restrict__ x, const float* __restrict__ w1, const float* __restrict__ b1,
    float* __restrict__ hsT, float* __restrict__ hr)
{
    int blk = blockIdx.x;
    int b  = blk / (SS/TILE);
    int s0 = (blk % (SS/TILE)) * TILE;
    int h = threadIdx.x;
    __shared__ float xL[TILE][HH];
    for (int t = 0; t < TILE; ++t) xL[t][h] = x[(b*SS+s0+t)*HH + h];
    __syncthreads();
    float as[TILE], ar[TILE];
    #pragma unroll
    for (int t = 0; t < TILE; ++t){ as[t] = 0.f; ar[t] = 0.f; }
    for (int c = 0; c < HH; ++c){
        float wsv = w1[c*HH + h];
        float wrv = w1[(HH+c)*HH + h];
        #pragma unroll
        for (int t = 0; t < TILE; ++t){
            as[t] = fmaf(xL[t][c], wsv, as[t]);
            ar[t] = fmaf(xL[t][c], wrv, ar[t]);
        }
    }
    float b1v = b1[h];
    for (int t = 0; t < TILE; ++t){
        hsT[((size_t)b*HH + h)*SS + s0 + t] = as[t];
        hr[(b*SS+s0+t)*HH + h] = ar[t] + b1v;
    }
}

// ---------------- K5: fused edge-logits + gumbel argmax -> adj ---------------
__global__ __launch_bounds__(128) void k_adj(
    const float* __restrict__ hsT, const float* __restrict__ hr,
    const float* __restrict__ w2, const float* __restrict__ b2,
    const float* __restrict__ gu, float* __restrict__ adj)
{
    int bi = blockIdx.x;           // b*SS + i
    int b = bi / SS; int i = bi % SS;
    int j = threadIdx.x;
    __shared__ float hriL[HH], w20L[HH], w21L[HH];
    hriL[j] = hr[bi*HH + j];       // hr already includes b1
    w20L[j] = w2[j*2 + 0];
    w21L[j] = w2[j*2 + 1];
    __syncthreads();
    const float* hsb = hsT + (size_t)b*HH*SS;
    float d0 = 0.f, d1 = 0.f;
    for (int h = 0; h < HH; ++h){
        float r = fmaxf(hsb[h*SS + j] + hriL[h], 0.f);
        d0 = fmaf(r, w20L[h], d0);
        d1 = fmaf(r, w21L[h], d1);
    }
    float2 uv = *reinterpret_cast<const float2*>(gu + ((size_t)bi*SS + j)*2);
    float u0 = fminf(fmaxf(uv.x, 1e-6f), 0.999999f);
    float u1 = fminf(fmaxf(uv.y, 1e-6f), 0.999999f);
    float g0 = -logf(-logf(u0));
    float g1 = -logf(-logf(u1));
    float y0 = d0 + b2[0] + g0;
    float y1 = d1 + b2[1] + g1;
    adj[(size_t)bi*SS + j] = (j > i && y0 >= y1) ? 1.f : 0.f;
}

// ---------------- K6: column degree ------------------------------------------
__global__ __launch_bounds__(128) void k_deg(
    const float* __restrict__ adj, float* __restrict__ deg)
{
    int b = blockIdx.x; int j = threadIdx.x;
    float s = 0.f;
    for (int i = 0; i < SS; ++i) s += adj[((size_t)b*SS + i)*SS + j];
    deg[b*SS + j] = fmaxf(s, 1.f);
}

// ---------------- K7a: agg = (adj^T @ xn) / deg -------------------------------
template<int JT>
__global__ __launch_bounds__(128) void k_agg(
    const float* __restrict__ adj, const float* __restrict__ xn,
    const float* __restrict__ deg, float* __restrict__ agg)
{
    int blk = blockIdx.x;
    int b  = blk / (SS/JT);
    int j0 = (blk % (SS/JT)) * JT;
    int h = threadIdx.x;
    __shared__ float adjL[SS][JT];
    for (int idx = h; idx < SS*JT; idx += 128){
        int i = idx / JT, jt = idx % JT;
        adjL[i][jt] = adj[((size_t)b*SS + i)*SS + j0 + jt];
    }
    __syncthreads();
    float acc[JT];
    #pragma unroll
    for (int t = 0; t < JT; ++t) acc[t] = 0.f;
    for (int i = 0; i < SS; ++i){
        float xv = xn[(b*SS+i)*HH + h];
        #pragma unroll
        for (int t = 0; t < JT; ++t) acc[t] = fmaf(adjL[i][t], xv, acc[t]);
    }
    for (int t = 0; t < JT; ++t)
        agg[(b*SS + j0 + t)*HH + h] = acc[t] / deg[b*SS + j0 + t];
}

// ---------------- K7b: out = agg@wl + bl + xn@wr ------------------------------
template<int TILE>
__global__ __launch_bounds__(128) void k_gnn_lin(
    const float* __restrict__ agg, const float* __restrict__ xn,
    const float* __restrict__ wl, const float* __restrict__ bl,
    const float* __restrict__ wr, float* __restrict__ out)
{
    int blk = blockIdx.x;
    int b  = blk / (SS/TILE);
    int s0 = (blk % (SS/TILE)) * TILE;
    int h = threadIdx.x;
    __shared__ float aggL[TILE][HH], xnL[TILE][HH];
    for (int t = 0; t < TILE; ++t){
        int r = (b*SS+s0+t)*HH + h;
        aggL[t][h] = agg[r]; xnL[t][h] = xn[r];
    }
    __syncthreads();
    float acc[TILE];
    float bv = bl[h];
    #pragma unroll
    for (int t = 0; t < TILE; ++t) acc[t] = bv;
    for (int c = 0; c < HH; ++c){
        float wlv = wl[c*HH + h];
        float wrv = wr[c*HH + h];
        #pragma unroll
        for (int t = 0; t < TILE; ++t){
            acc[t] = fmaf(aggL[t][c], wlv, acc[t]);
            acc[t] = fmaf(xnL[t][c], wrv, acc[t]);
        }
    }
    for (int t = 0; t < TILE; ++t) out[(b*SS+s0+t)*HH + h] = acc[t];
}

// ---------------- K8: BN stats (double accum) -> scale/shift ------------------
__global__ __launch_bounds__(256) void k_bnstats(
    const float* __restrict__ out, const float* __restrict__ gamma,
    const float* __restrict__ beta, float* __restrict__ scale, float* __restrict__ shift)
{
    int h = blockIdx.x; int t = threadIdx.x;
    double s = 0.0, s2 = 0.0;
    for (int i = t; i < BB*SS; i += 256){
        float v = out[(size_t)i*HH + h];
        s += v; s2 += (double)v*v;
    }
    __shared__ double sh[256], sh2[256];
    sh[t] = s; sh2[t] = s2;
    __syncthreads();
    for (int off = 128; off; off >>= 1){
        if (t < off){ sh[t] += sh[t+off]; sh2[t] += sh2[t+off]; }
        __syncthreads();
    }
    if (t == 0){
        double m = sh[0] / (BB*SS);
        double v = sh2[0] / (BB*SS) - m*m;
        if (v < 0.0) v = 0.0;
        float sc = gamma[h] * (float)(1.0 / sqrt(v + 1e-5));
        scale[h] = sc;
        shift[h] = beta[h] - (float)m * sc;
    }
}

// ---------------- K9: BN apply, write xn, capture s=S-1 slice -----------------
__global__ __launch_bounds__(256) void k_bnapply(
    const float* __restrict__ out, const float* __restrict__ scale,
    const float* __restrict__ shift, float* __restrict__ xn, float* __restrict__ out_last)
{
    int idx = blockIdx.x*256 + threadIdx.x;   // NBSH is multiple of 256
    int h = idx % HH; int bs = idx / HH;
    float v = out[idx]*scale[h] + shift[h];
    xn[idx] = v;
    if ((bs % SS) == SS-1) out_last[(bs/SS)*HH + h] = v;
}

// ---------------- K10: head (gate -> we -> wo) --------------------------------
__global__ __launch_bounds__(64) void k_head(
    const float* __restrict__ out_last, const float* __restrict__ wg,
    const float* __restrict__ bg, const float* __restrict__ we,
    const float* __restrict__ be, const float* __restrict__ wo,
    const float* __restrict__ bo, float* __restrict__ out)
{
    int b = blockIdx.x; int t = threadIdx.x;
    __shared__ float xw[HH];
    for (int h = t; h < HH; h += 64){
        float a = bg[0];
        #pragma unroll
        for (int l = 0; l < 3; ++l) a = fmaf(out_last[l*BB*HH + b*HH + h], wg[l], a);
        xw[h] = fmaxf(a, 0.f);
    }
    __syncthreads();
    float acc = be[t];
    for (int h = 0; h < HH; ++h) acc = fmaf(xw[h], we[h*64 + t], acc);
    float h2 = fmaxf(acc, 0.f);
    float r = h2 * wo[t];
    #pragma unroll
    for (int off = 32; off; off >>= 1) r += __shfl_down(r, off, 64);
    if (t == 0) out[b] = r + bo[0];
}

// ------------------------------------------------------------------------------
extern "C" void kernel_launch(void* const* d_in, const int* in_sizes, int n_in,
                              void* d_out, int out_size, void* d_ws, size_t ws_size,
                              hipStream_t stream)
{
    const float* data = (const float*)d_in[0];
    const float* gu   = (const float*)d_in[1];
    const float* w11  = (const float*)d_in[2];
    const float* b11  = (const float*)d_in[3];
    const float* w12  = (const float*)d_in[4];
    const float* b12  = (const float*)d_in[5];
    const float* w21  = (const float*)d_in[6];
    const float* b21  = (const float*)d_in[7];
    const float* w22  = (const float*)d_in[8];
    const float* b22  = (const float*)d_in[9];
    const float* w31  = (const float*)d_in[10];
    const float* b31  = (const float*)d_in[11];
    const float* wf   = (const float*)d_in[12];
    const float* bf   = (const float*)d_in[13];
    const float* w1   = (const float*)d_in[14];
    const float* b1   = (const float*)d_in[15];
    const float* w2   = (const float*)d_in[16];
    const float* b2   = (const float*)d_in[17];
    const float* wl   = (const float*)d_in[18];
    const float* bl   = (const float*)d_in[19];
    const float* wr   = (const float*)d_in[20];
    const float* gamma= (const float*)d_in[21];
    const float* beta = (const float*)d_in[22];
    const float* wg   = (const float*)d_in[23];
    const float* bg   = (const float*)d_in[24];
    const float* we   = (const float*)d_in[25];
    const float* be   = (const float*)d_in[26];
    const float* wo   = (const float*)d_in[27];
    const float* bo   = (const float*)d_in[28];
    float* out = (float*)d_out;

    float* ws = (float*)d_ws;
    float* R0 = ws;               // t1 -> x (xn)
    float* R1 = ws + (size_t)NBSH;   // t2 -> hsT -> agg
    float* R2 = ws + (size_t)2*NBSH; // t3 -> hr
    float* R3 = ws + (size_t)3*NBSH; // x1 -> adj
    float* R4 = ws + (size_t)4*NBSH; // x2 -> out_buf
    float* deg      = ws + (size_t)5*NBSH;
    float* out_last = deg + BB*SS;
    float* scale    = out_last + 3*BB*HH;
    float* shift    = scale + HH;

    k_pointwise<<<BB*SS, 128, 0, stream>>>(data, w11,b11, w21,b21, w31,b31, R0, R1, R2);
    k_dilconv<3,3,16><<<BB*(SS/16), 128, 0, stream>>>(R0, w12, b12, R3);
    k_dilconv<5,5,16><<<BB*(SS/16), 128, 0, stream>>>(R1, w22, b22, R4);
    k_fuse<16><<<BB*(SS/16), 128, 0, stream>>>(R3, R4, R2, wf, bf, R0);
    k_hs_hr<16><<<BB*(SS/16), 128, 0, stream>>>(R0, w1, b1, R1, R2);
    k_adj<<<BB*SS, 128, 0, stream>>>(R1, R2, w2, b2, gu, R3);
    k_deg<<<BB, 128, 0, stream>>>(R3, deg);
    for (int l = 0; l < 3; ++l){
        k_agg<32><<<BB*(SS/32), 128, 0, stream>>>(R3, R0, deg, R1);
        k_gnn_lin<16><<<BB*(SS/16), 128, 0, stream>>>(R1, R0,
            wl + (size_t)l*HH*HH, bl + (size_t)l*HH, wr + (size_t)l*HH*HH, R4);
        k_bnstats<<<HH, 256, 0, stream>>>(R4, gamma + (size_t)l*HH, beta + (size_t)l*HH, scale, shift);
        k_bnapply<<<NBSH/256, 256, 0, stream>>>(R4, scale, shift, R0, out_last + (size_t)l*BB*HH);
    }
    k_head<<<BB, 64, 0, stream>>>(out_last, wg, bg, we, be, wo, bo, out);
}

// Round 2
// 185.644 us; speedup vs baseline: 2.2234x; 2.2234x over previous
//
#include <hip/hip_runtime.h>
#include <math.h>

#define BB 32
#define SS 128
#define DIN 16
#define HH 128
#define NBSH (BB*SS*HH)   // 524288

// ============ K0: transpose conv weights to [k][c][h] for coalesced loads ====
__global__ __launch_bounds__(128) void k_prep(
    const float* __restrict__ w12, const float* __restrict__ w22,
    float* __restrict__ wT3, float* __restrict__ wT5)
{
    int c0 = blockIdx.x; int h = threadIdx.x;
    if (c0 < HH){
        int c = c0;
        #pragma unroll
        for (int k = 0; k < 3; ++k)
            wT3[(k*HH+c)*HH + h] = w12[((size_t)h*HH + c)*3 + k];
    } else {
        int c = c0 - HH;
        #pragma unroll
        for (int k = 0; k < 5; ++k)
            wT5[(k*HH+c)*HH + h] = w22[((size_t)h*HH + c)*5 + k];
    }
}

// ============ K1: fused pointwise(1x1) + both dilated convs ===================
// block = (b, 4-row tile). t1/t2 computed with halo into LDS (transposed [c][r]),
// then conv3(d=3) -> x1, conv5(d=5) -> x2; t3 (1x1) written directly.
__global__ __launch_bounds__(128) void k_front(
    const float* __restrict__ data,
    const float* __restrict__ w11, const float* __restrict__ b11,
    const float* __restrict__ w21, const float* __restrict__ b21,
    const float* __restrict__ w31, const float* __restrict__ b31,
    const float* __restrict__ wT3, const float* __restrict__ b12,
    const float* __restrict__ wT5, const float* __restrict__ b22,
    float* __restrict__ x1, float* __restrict__ x2, float* __restrict__ t3)
{
    int blk = blockIdx.x;
    int b  = blk >> 5;
    int s0 = (blk & 31) * 4;
    int h = threadIdx.x;
    __shared__ float dinL[24*DIN];     // data rows s0-10 .. s0+13
    __shared__ float tPT[HH*12];       // t1, [c][r], r=0..9 (pad 12), s = s0-3+r
    __shared__ float tQT[HH*24];       // t2, [c][r], r=0..23,        s = s0-10+r

    for (int idx = h; idx < 24*DIN; idx += 128){
        int r = idx >> 4, c = idx & 15;
        int sp = s0 - 10 + r;
        dinL[idx] = (sp >= 0 && sp < SS) ? data[(b*SS+sp)*DIN + c] : 0.f;
    }
    float w11r[DIN], w21r[DIN], w31r[DIN];
    #pragma unroll
    for (int c = 0; c < DIN; ++c){
        w11r[c] = w11[h*DIN+c]; w21r[c] = w21[h*DIN+c]; w31r[c] = w31[h*DIN+c];
    }
    float bv11 = b11[h], bv21 = b21[h], bv31 = b31[h];
    __syncthreads();

    for (int r = 0; r < 24; ++r){
        int sp = s0 - 10 + r;
        bool valid = (sp >= 0 && sp < SS);
        const float* dr = dinL + r*DIN;
        float a2 = 0.f;
        if (valid){
            a2 = bv21;
            #pragma unroll
            for (int c = 0; c < DIN; ++c) a2 = fmaf(dr[c], w21r[c], a2);
        }
        tQT[h*24 + r] = a2;
        if (r >= 7 && r < 17){
            float a1 = 0.f;
            if (valid){
                a1 = bv11;
                #pragma unroll
                for (int c = 0; c < DIN; ++c) a1 = fmaf(dr[c], w11r[c], a1);
            }
            tPT[h*12 + (r-7)] = a1;
        }
        if (r >= 10 && r < 14){   // s = s0 .. s0+3, always valid
            float a3 = bv31;
            #pragma unroll
            for (int c = 0; c < DIN; ++c) a3 = fmaf(dr[c], w31r[c], a3);
            t3[(b*SS+sp)*HH + h] = a3;
        }
    }
    __syncthreads();

    float acc3[4], acc5[4];
    float bv12 = b12[h], bv22 = b22[h];
    #pragma unroll
    for (int t = 0; t < 4; ++t){ acc3[t] = bv12; acc5[t] = bv22; }

    for (int c = 0; c < HH; ++c){
        const float4* pp = reinterpret_cast<const float4*>(tPT + c*12);
        float4 p0 = pp[0], p1 = pp[1], p2 = pp[2];
        const float4* qq = reinterpret_cast<const float4*>(tQT + c*24);
        float4 q0 = qq[0], q1 = qq[1], q2 = qq[2], q3 = qq[3], q4 = qq[4], q5 = qq[5];
        float pr[12] = {p0.x,p0.y,p0.z,p0.w, p1.x,p1.y,p1.z,p1.w, p2.x,p2.y,p2.z,p2.w};
        float qr[24] = {q0.x,q0.y,q0.z,q0.w, q1.x,q1.y,q1.z,q1.w, q2.x,q2.y,q2.z,q2.w,
                        q3.x,q3.y,q3.z,q3.w, q4.x,q4.y,q4.z,q4.w, q5.x,q5.y,q5.z,q5.w};
        float w3v[3], w5v[5];
        #pragma unroll
        for (int k = 0; k < 3; ++k) w3v[k] = wT3[(k*HH+c)*HH + h];
        #pragma unroll
        for (int k = 0; k < 5; ++k) w5v[k] = wT5[(k*HH+c)*HH + h];
        #pragma unroll
        for (int t = 0; t < 4; ++t){
            #pragma unroll
            for (int k = 0; k < 3; ++k) acc3[t] = fmaf(pr[t+3*k], w3v[k], acc3[t]);
            #pragma unroll
            for (int k = 0; k < 5; ++k) acc5[t] = fmaf(qr[t+5*k], w5v[k], acc5[t]);
        }
    }
    #pragma unroll
    for (int t = 0; t < 4; ++t){
        x1[(b*SS+s0+t)*HH + h] = acc3[t];
        x2[(b*SS+s0+t)*HH + h] = acc5[t];
    }
}

// ============ K2: concat+fuse GEMM (K=384) + relu, then hs(T) and hr ==========
__global__ __launch_bounds__(128) void k_fuse_hs(
    const float* __restrict__ x1, const float* __restrict__ x2, const float* __restrict__ t3,
    const float* __restrict__ wf, const float* __restrict__ bf,
    const float* __restrict__ w1, const float* __restrict__ b1,
    float* __restrict__ x, float* __restrict__ hsT, float* __restrict__ hr)
{
    int blk = blockIdx.x; int b = blk>>5; int s0 = (blk&31)*4; int h = threadIdx.x;
    __shared__ float4 aL1[HH], aL2[HH], aL3[HH], xL[HH];
    size_t base = (size_t)(b*SS+s0)*HH + h;
    aL1[h] = make_float4(x1[base], x1[base+HH], x1[base+2*HH], x1[base+3*HH]);
    aL2[h] = make_float4(x2[base], x2[base+HH], x2[base+2*HH], x2[base+3*HH]);
    aL3[h] = make_float4(t3[base], t3[base+HH], t3[base+2*HH], t3[base+3*HH]);
    __syncthreads();

    float bfv = bf[h];
    float acc[4] = {bfv,bfv,bfv,bfv};
    for (int c = 0; c < HH; ++c){
        float4 a = aL1[c]; float w = wf[c*HH + h];
        acc[0]=fmaf(a.x,w,acc[0]); acc[1]=fmaf(a.y,w,acc[1]);
        acc[2]=fmaf(a.z,w,acc[2]); acc[3]=fmaf(a.w,w,acc[3]);
    }
    for (int c = 0; c < HH; ++c){
        float4 a = aL2[c]; float w = wf[(HH+c)*HH + h];
        acc[0]=fmaf(a.x,w,acc[0]); acc[1]=fmaf(a.y,w,acc[1]);
        acc[2]=fmaf(a.z,w,acc[2]); acc[3]=fmaf(a.w,w,acc[3]);
    }
    for (int c = 0; c < HH; ++c){
        float4 a = aL3[c]; float w = wf[(2*HH+c)*HH + h];
        acc[0]=fmaf(a.x,w,acc[0]); acc[1]=fmaf(a.y,w,acc[1]);
        acc[2]=fmaf(a.z,w,acc[2]); acc[3]=fmaf(a.w,w,acc[3]);
    }
    float4 xv = make_float4(fmaxf(acc[0],0.f), fmaxf(acc[1],0.f),
                            fmaxf(acc[2],0.f), fmaxf(acc[3],0.f));
    x[base] = xv.x; x[base+HH] = xv.y; x[base+2*HH] = xv.z; x[base+3*HH] = xv.w;
    xL[h] = xv;
    __syncthreads();

    float as[4]={0,0,0,0}, ar[4]={0,0,0,0};
    for (int c = 0; c < HH; ++c){
        float4 a = xL[c];
        float wsv = w1[c*HH+h], wrv = w1[(HH+c)*HH+h];
        as[0]=fmaf(a.x,wsv,as[0]); as[1]=fmaf(a.y,wsv,as[1]);
        as[2]=fmaf(a.z,wsv,as[2]); as[3]=fmaf(a.w,wsv,as[3]);
        ar[0]=fmaf(a.x,wrv,ar[0]); ar[1]=fmaf(a.y,wrv,ar[1]);
        ar[2]=fmaf(a.z,wrv,ar[2]); ar[3]=fmaf(a.w,wrv,ar[3]);
    }
    float b1v = b1[h];
    *reinterpret_cast<float4*>(hsT + ((size_t)b*HH + h)*SS + s0) =
        make_float4(as[0], as[1], as[2], as[3]);
    hr[base]      = ar[0] + b1v;
    hr[base+HH]   = ar[1] + b1v;
    hr[base+2*HH] = ar[2] + b1v;
    hr[base+3*HH] = ar[3] + b1v;
}

// ============ K3: fused edge-logits + gumbel argmax -> adj ====================
__global__ __launch_bounds__(128) void k_adj(
    const float* __restrict__ hsT, const float* __restrict__ hr,
    const float* __restrict__ w2, const float* __restrict__ b2,
    const float* __restrict__ gu, float* __restrict__ adj)
{
    int bi = blockIdx.x;           // b*SS + i
    int b = bi >> 7; int i = bi & 127;
    int j = threadIdx.x;
    __shared__ float hriL[HH], w20L[HH], w21L[HH];
    hriL[j] = hr[(size_t)bi*HH + j];
    w20L[j] = w2[j*2 + 0];
    w21L[j] = w2[j*2 + 1];
    __syncthreads();
    const float* hsb = hsT + (size_t)b*HH*SS;
    float d0 = 0.f, d1 = 0.f;
    #pragma unroll 4
    for (int h = 0; h < HH; ++h){
        float r = fmaxf(hsb[h*SS + j] + hriL[h], 0.f);
        d0 = fmaf(r, w20L[h], d0);
        d1 = fmaf(r, w21L[h], d1);
    }
    float2 uv = *reinterpret_cast<const float2*>(gu + ((size_t)bi*SS + j)*2);
    float u0 = fminf(fmaxf(uv.x, 1e-6f), 0.999999f);
    float u1 = fminf(fmaxf(uv.y, 1e-6f), 0.999999f);
    float g0 = -logf(-logf(u0));
    float g1 = -logf(-logf(u1));
    float y0 = d0 + b2[0] + g0;
    float y1 = d1 + b2[1] + g1;
    adj[(size_t)bi*SS + j] = (j > i && y0 >= y1) ? 1.f : 0.f;
}

// ============ K4: column degree -> reciprocal =================================
__global__ __launch_bounds__(128) void k_deg(
    const float* __restrict__ adj, float* __restrict__ dinv)
{
    int b = blockIdx.x; int j = threadIdx.x;
    float s = 0.f;
    for (int i = 0; i < SS; ++i) s += adj[(size_t)(b*SS+i)*SS + j];
    dinv[b*SS+j] = 1.f / fmaxf(s, 1.f);
}

// ============ K5: agg = (adj^T @ xn_eff) * dinv  (xn_eff = in*sc+sh) ==========
__global__ __launch_bounds__(128) void k_agg(
    const float* __restrict__ adj, const float* __restrict__ in,
    const float* __restrict__ dinv,
    const float* __restrict__ scale, const float* __restrict__ shift, int aff,
    float* __restrict__ agg)
{
    int blk = blockIdx.x; int b = blk>>5; int j0 = (blk&31)*4; int h = threadIdx.x;
    __shared__ float4 adjL[SS];
    adjL[h] = *reinterpret_cast<const float4*>(adj + (size_t)(b*SS+h)*SS + j0);
    float sc = aff ? scale[h] : 1.f;
    float sh = aff ? shift[h] : 0.f;
    __syncthreads();
    float a0=0.f, a1=0.f, a2=0.f, a3=0.f;
    const float* inb = in + (size_t)b*SS*HH + h;
    #pragma unroll 4
    for (int i = 0; i < SS; ++i){
        float xv = fmaf(inb[(size_t)i*HH], sc, sh);
        float4 av = adjL[i];
        a0=fmaf(av.x,xv,a0); a1=fmaf(av.y,xv,a1);
        a2=fmaf(av.z,xv,a2); a3=fmaf(av.w,xv,a3);
    }
    float4 dv = *reinterpret_cast<const float4*>(dinv + b*SS + j0);
    agg[(size_t)(b*SS+j0+0)*HH + h] = a0*dv.x;
    agg[(size_t)(b*SS+j0+1)*HH + h] = a1*dv.y;
    agg[(size_t)(b*SS+j0+2)*HH + h] = a2*dv.z;
    agg[(size_t)(b*SS+j0+3)*HH + h] = a3*dv.w;
}

// ============ K6: out = agg@wl + bl + xn_eff@wr, + BN partial stats ===========
__global__ __launch_bounds__(128) void k_gnn_lin(
    const float* __restrict__ agg, const float* __restrict__ in,
    const float* __restrict__ scale_in, const float* __restrict__ shift_in, int aff,
    const float* __restrict__ wl, const float* __restrict__ bl,
    const float* __restrict__ wr,
    float* __restrict__ outb, float* __restrict__ part)
{
    int blk = blockIdx.x; int b = blk>>5; int s0 = (blk&31)*4; int h = threadIdx.x;
    __shared__ float4 aggL[HH], xnL[HH];
    size_t base = (size_t)(b*SS+s0)*HH + h;
    aggL[h] = make_float4(agg[base], agg[base+HH], agg[base+2*HH], agg[base+3*HH]);
    float sc = aff ? scale_in[h] : 1.f;
    float sh = aff ? shift_in[h] : 0.f;
    xnL[h] = make_float4(fmaf(in[base],sc,sh), fmaf(in[base+HH],sc,sh),
                         fmaf(in[base+2*HH],sc,sh), fmaf(in[base+3*HH],sc,sh));
    __syncthreads();
    float bv = bl[h];
    float acc[4] = {bv,bv,bv,bv};
    for (int c = 0; c < HH; ++c){
        float4 g = aggL[c]; float4 xv = xnL[c];
        float wlv = wl[c*HH+h], wrv = wr[c*HH+h];
        acc[0]=fmaf(g.x,wlv,acc[0]); acc[0]=fmaf(xv.x,wrv,acc[0]);
        acc[1]=fmaf(g.y,wlv,acc[1]); acc[1]=fmaf(xv.y,wrv,acc[1]);
        acc[2]=fmaf(g.z,wlv,acc[2]); acc[2]=fmaf(xv.z,wrv,acc[2]);
        acc[3]=fmaf(g.w,wlv,acc[3]); acc[3]=fmaf(xv.w,wrv,acc[3]);
    }
    outb[base]      = acc[0];
    outb[base+HH]   = acc[1];
    outb[base+2*HH] = acc[2];
    outb[base+3*HH] = acc[3];
    float psum = acc[0]+acc[1]+acc[2]+acc[3];
    float psq  = acc[0]*acc[0]+acc[1]*acc[1]+acc[2]*acc[2]+acc[3]*acc[3];
    part[h*1024 + blk]          = psum;   // transposed layout -> coalesced bnfin reads
    part[131072 + h*1024 + blk] = psq;
}

// ============ K7: BN finalize (scale/shift) + capture normalized last row =====
__global__ __launch_bounds__(256) void k_bnfin(
    const float* __restrict__ part, const float* __restrict__ gamma,
    const float* __restrict__ beta, const float* __restrict__ outb,
    float* __restrict__ scale, float* __restrict__ shift, float* __restrict__ ol)
{
    int h = blockIdx.x; int t = threadIdx.x;
    float s1 = 0.f, s2 = 0.f;
    for (int i = t; i < 1024; i += 256){
        s1 += part[h*1024 + i];
        s2 += part[131072 + h*1024 + i];
    }
    __shared__ float r1[256], r2[256];
    __shared__ float sc_sh[2];
    r1[t] = s1; r2[t] = s2;
    __syncthreads();
    for (int off = 128; off; off >>= 1){
        if (t < off){ r1[t] += r1[t+off]; r2[t] += r2[t+off]; }
        __syncthreads();
    }
    if (t == 0){
        float m = r1[0] * (1.f/4096.f);
        float v = r2[0] * (1.f/4096.f) - m*m;
        v = fmaxf(v, 0.f);
        float sc = gamma[h] / sqrtf(v + 1e-5f);
        float sh = beta[h] - m*sc;
        scale[h] = sc; shift[h] = sh;
        sc_sh[0] = sc; sc_sh[1] = sh;
    }
    __syncthreads();
    if (t < BB){
        float val = outb[((size_t)t*SS + SS-1)*HH + h];
        ol[t*HH + h] = fmaf(val, sc_sh[0], sc_sh[1]);
    }
}

// ============ K8: head (gate -> we -> wo) =====================================
__global__ __launch_bounds__(128) void k_head(
    const float* __restrict__ ol, const float* __restrict__ wg,
    const float* __restrict__ bg, const float* __restrict__ we,
    const float* __restrict__ be, const float* __restrict__ wo,
    const float* __restrict__ bo, float* __restrict__ out)
{
    int b = blockIdx.x; int t = threadIdx.x;
    __shared__ float xw[HH];
    float a = bg[0];
    #pragma unroll
    for (int l = 0; l < 3; ++l) a = fmaf(ol[(l*BB + b)*HH + t], wg[l], a);
    xw[t] = fmaxf(a, 0.f);
    __syncthreads();
    if (t < 64){
        float acc = be[t];
        for (int h = 0; h < HH; ++h) acc = fmaf(xw[h], we[h*64 + t], acc);
        float h2 = fmaxf(acc, 0.f);
        float r = h2 * wo[t];
        #pragma unroll
        for (int off = 32; off; off >>= 1) r += __shfl_down(r, off, 64);
        if (t == 0) out[b] = r + bo[0];
    }
}

// ==============================================================================
extern "C" void kernel_launch(void* const* d_in, const int* in_sizes, int n_in,
                              void* d_out, int out_size, void* d_ws, size_t ws_size,
                              hipStream_t stream)
{
    const float* data = (const float*)d_in[0];
    const float* gu   = (const float*)d_in[1];
    const float* w11  = (const float*)d_in[2];
    const float* b11  = (const float*)d_in[3];
    const float* w12  = (const float*)d_in[4];
    const float* b12  = (const float*)d_in[5];
    const float* w21  = (const float*)d_in[6];
    const float* b21  = (const float*)d_in[7];
    const float* w22  = (const float*)d_in[8];
    const float* b22  = (const float*)d_in[9];
    const float* w31  = (const float*)d_in[10];
    const float* b31  = (const float*)d_in[11];
    const float* wf   = (const float*)d_in[12];
    const float* bf   = (const float*)d_in[13];
    const float* w1   = (const float*)d_in[14];
    const float* b1   = (const float*)d_in[15];
    const float* w2   = (const float*)d_in[16];
    const float* b2   = (const float*)d_in[17];
    const float* wl   = (const float*)d_in[18];
    const float* bl   = (const float*)d_in[19];
    const float* wr   = (const float*)d_in[20];
    const float* gamma= (const float*)d_in[21];
    const float* beta = (const float*)d_in[22];
    const float* wg   = (const float*)d_in[23];
    const float* bg   = (const float*)d_in[24];
    const float* we   = (const float*)d_in[25];
    const float* be   = (const float*)d_in[26];
    const float* wo   = (const float*)d_in[27];
    const float* bo   = (const float*)d_in[28];
    float* out = (float*)d_out;

    // workspace layout (floats); ~9.5 MB total
    float* ws = (float*)d_ws;
    float* P = ws;                       // x1 -> hr -> agg (per layer)
    float* Q = ws + (size_t)NBSH;        // x2 -> adj
    float* R = ws + (size_t)2*NBSH;      // t3 -> x -> out1
    float* S = ws + (size_t)3*NBSH;      // hsT -> out0 -> out2
    float* G = ws + (size_t)4*NBSH;      // wT3|wT5 (prep/front), then BN partials
    float* wT3   = G;                    // 3*128*128 = 49152
    float* wT5   = G + 49152;            // 5*128*128 = 81920
    float* dinv  = G + 262144;           // 4096
    float* scale = dinv + BB*SS;         // 3*128
    float* shift = scale + 3*HH;         // 3*128
    float* OL    = shift + 3*HH;         // 3*32*128

    k_prep<<<256, 128, 0, stream>>>(w12, w22, wT3, wT5);
    k_front<<<1024, 128, 0, stream>>>(data, w11,b11, w21,b21, w31,b31,
                                      wT3, b12, wT5, b22, P, Q, R);
    k_fuse_hs<<<1024, 128, 0, stream>>>(P, Q, R, wf, bf, w1, b1, R, S, P);
    k_adj<<<BB*SS, 128, 0, stream>>>(S, P, w2, b2, gu, Q);
    k_deg<<<BB, 128, 0, stream>>>(Q, dinv);

    const float* inl[3] = {R, S, R};
    float* outl[3]      = {S, R, S};
    for (int l = 0; l < 3; ++l){
        int aff = (l > 0);
        const float* sc = scale + (l>0 ? (l-1)*HH : 0);
        const float* sh = shift + (l>0 ? (l-1)*HH : 0);
        k_agg<<<1024, 128, 0, stream>>>(Q, inl[l], dinv, sc, sh, aff, P);
        k_gnn_lin<<<1024, 128, 0, stream>>>(P, inl[l], sc, sh, aff,
            wl + (size_t)l*HH*HH, bl + (size_t)l*HH, wr + (size_t)l*HH*HH,
            outl[l], G);
        k_bnfin<<<HH, 256, 0, stream>>>(G, gamma + (size_t)l*HH, beta + (size_t)l*HH,
            outl[l], scale + l*HH, shift + l*HH, OL + (size_t)l*BB*HH);
    }
    k_head<<<BB, 128, 0, stream>>>(OL, wg, bg, we, be, wo, bo, out);
}

// Round 3
// 181.886 us; speedup vs baseline: 2.2693x; 1.0207x over previous
//
#include <hip/hip_runtime.h>
#include <math.h>

#define BB 32
#define SS 128
#define DIN 16
#define HH 128
#define NBSH (BB*SS*HH)   // 524288

__device__ __forceinline__ float4 f4add(float4 a, float4 b){
    return make_float4(a.x+b.x, a.y+b.y, a.z+b.z, a.w+b.w);
}

// ============ K0: transpose conv weights to [k][c][h] for coalesced loads ====
__global__ __launch_bounds__(128) void k_prep(
    const float* __restrict__ w12, const float* __restrict__ w22,
    float* __restrict__ wT3, float* __restrict__ wT5)
{
    int c0 = blockIdx.x; int h = threadIdx.x;
    if (c0 < HH){
        int c = c0;
        #pragma unroll
        for (int k = 0; k < 3; ++k)
            wT3[(k*HH+c)*HH + h] = w12[((size_t)h*HH + c)*3 + k];
    } else {
        int c = c0 - HH;
        #pragma unroll
        for (int k = 0; k < 5; ++k)
            wT5[(k*HH+c)*HH + h] = w22[((size_t)h*HH + c)*5 + k];
    }
}

// ============ K1: pointwise + dilated conv; blocks split by conv type =========
// blocks [0,1024): conv3 (t1 halo 10 rows) + t3 direct
// blocks [1024,2048): conv5 (t2 halo 24 rows)
__global__ __launch_bounds__(128) void k_front(
    const float* __restrict__ data,
    const float* __restrict__ w11, const float* __restrict__ b11,
    const float* __restrict__ w21, const float* __restrict__ b21,
    const float* __restrict__ w31, const float* __restrict__ b31,
    const float* __restrict__ wT3, const float* __restrict__ b12,
    const float* __restrict__ wT5, const float* __restrict__ b22,
    float* __restrict__ x1, float* __restrict__ x2, float* __restrict__ t3)
{
    __shared__ float sb[384 + 3072];   // din (<=24*16) | tbuf (<=128*24)
    float* dinL = sb;
    float* tb   = sb + 384;
    int blk = blockIdx.x;
    int h = threadIdx.x;

    if (blk < 1024){
        // ---------------- conv3 path (dil=3) + t3 ----------------
        int b = blk >> 5; int s0 = (blk & 31) * 4;
        for (int idx = h; idx < 10*DIN; idx += 128){
            int r = idx >> 4, c = idx & 15;
            int sp = s0 - 3 + r;
            dinL[idx] = (sp >= 0 && sp < SS) ? data[(b*SS+sp)*DIN + c] : 0.f;
        }
        float w11r[DIN], w31r[DIN];
        #pragma unroll
        for (int c = 0; c < DIN; ++c){ w11r[c] = w11[h*DIN+c]; w31r[c] = w31[h*DIN+c]; }
        float bv11 = b11[h], bv31 = b31[h];
        __syncthreads();
        for (int r = 0; r < 10; ++r){
            int sp = s0 - 3 + r;
            bool valid = (sp >= 0 && sp < SS);
            const float* dr = dinL + r*DIN;
            float a1 = 0.f;
            if (valid){
                a1 = bv11;
                #pragma unroll
                for (int c = 0; c < DIN; ++c) a1 = fmaf(dr[c], w11r[c], a1);
            }
            tb[h*12 + r] = a1;
            if (r >= 3 && r < 7){
                float a3 = bv31;
                #pragma unroll
                for (int c = 0; c < DIN; ++c) a3 = fmaf(dr[c], w31r[c], a3);
                t3[(b*SS+sp)*HH + h] = a3;
            }
        }
        __syncthreads();
        float bv12 = b12[h];
        float acc[4] = {bv12,bv12,bv12,bv12};
        for (int c = 0; c < HH; ++c){
            const float4* pp = reinterpret_cast<const float4*>(tb + c*12);
            float4 p0 = pp[0], p1 = pp[1], p2 = pp[2];
            float pr[12] = {p0.x,p0.y,p0.z,p0.w, p1.x,p1.y,p1.z,p1.w, p2.x,p2.y,p2.z,p2.w};
            float w3v[3];
            #pragma unroll
            for (int k = 0; k < 3; ++k) w3v[k] = wT3[(k*HH+c)*HH + h];
            #pragma unroll
            for (int t = 0; t < 4; ++t){
                #pragma unroll
                for (int k = 0; k < 3; ++k) acc[t] = fmaf(pr[t+3*k], w3v[k], acc[t]);
            }
        }
        #pragma unroll
        for (int t = 0; t < 4; ++t) x1[(b*SS+s0+t)*HH + h] = acc[t];
    } else {
        // ---------------- conv5 path (dil=5) ----------------
        int cblk = blk - 1024;
        int b = cblk >> 5; int s0 = (cblk & 31) * 4;
        for (int idx = h; idx < 24*DIN; idx += 128){
            int r = idx >> 4, c = idx & 15;
            int sp = s0 - 10 + r;
            dinL[idx] = (sp >= 0 && sp < SS) ? data[(b*SS+sp)*DIN + c] : 0.f;
        }
        float w21r[DIN];
        #pragma unroll
        for (int c = 0; c < DIN; ++c) w21r[c] = w21[h*DIN+c];
        float bv21 = b21[h];
        __syncthreads();
        for (int r = 0; r < 24; ++r){
            int sp = s0 - 10 + r;
            bool valid = (sp >= 0 && sp < SS);
            const float* dr = dinL + r*DIN;
            float a2 = 0.f;
            if (valid){
                a2 = bv21;
                #pragma unroll
                for (int c = 0; c < DIN; ++c) a2 = fmaf(dr[c], w21r[c], a2);
            }
            tb[h*24 + r] = a2;
        }
        __syncthreads();
        float bv22 = b22[h];
        float acc[4] = {bv22,bv22,bv22,bv22};
        for (int c = 0; c < HH; ++c){
            const float4* qq = reinterpret_cast<const float4*>(tb + c*24);
            float4 q0 = qq[0], q1 = qq[1], q2 = qq[2], q3 = qq[3], q4 = qq[4], q5 = qq[5];
            float qr[24] = {q0.x,q0.y,q0.z,q0.w, q1.x,q1.y,q1.z,q1.w, q2.x,q2.y,q2.z,q2.w,
                            q3.x,q3.y,q3.z,q3.w, q4.x,q4.y,q4.z,q4.w, q5.x,q5.y,q5.z,q5.w};
            float w5v[5];
            #pragma unroll
            for (int k = 0; k < 5; ++k) w5v[k] = wT5[(k*HH+c)*HH + h];
            #pragma unroll
            for (int t = 0; t < 4; ++t){
                #pragma unroll
                for (int k = 0; k < 5; ++k) acc[t] = fmaf(qr[t+5*k], w5v[k], acc[t]);
            }
        }
        #pragma unroll
        for (int t = 0; t < 4; ++t) x2[(b*SS+s0+t)*HH + h] = acc[t];
    }
}

// ============ K2: concat+fuse GEMM (K=384) + relu, then hs(T) and hr ==========
__global__ __launch_bounds__(128) void k_fuse_hs(
    const float* __restrict__ x1, const float* __restrict__ x2, const float* __restrict__ t3,
    const float* __restrict__ wf, const float* __restrict__ bf,
    const float* __restrict__ w1, const float* __restrict__ b1,
    float* __restrict__ x, float* __restrict__ hsT, float* __restrict__ hr)
{
    int blk = blockIdx.x; int b = blk>>5; int s0 = (blk&31)*4; int h = threadIdx.x;
    __shared__ float4 aL1[HH], aL2[HH], aL3[HH], xL[HH];
    size_t base = (size_t)(b*SS+s0)*HH + h;
    aL1[h] = make_float4(x1[base], x1[base+HH], x1[base+2*HH], x1[base+3*HH]);
    aL2[h] = make_float4(x2[base], x2[base+HH], x2[base+2*HH], x2[base+3*HH]);
    aL3[h] = make_float4(t3[base], t3[base+HH], t3[base+2*HH], t3[base+3*HH]);
    __syncthreads();

    float bfv = bf[h];
    float acc[4] = {bfv,bfv,bfv,bfv};
    for (int c = 0; c < HH; ++c){
        float4 a = aL1[c]; float w = wf[c*HH + h];
        acc[0]=fmaf(a.x,w,acc[0]); acc[1]=fmaf(a.y,w,acc[1]);
        acc[2]=fmaf(a.z,w,acc[2]); acc[3]=fmaf(a.w,w,acc[3]);
    }
    for (int c = 0; c < HH; ++c){
        float4 a = aL2[c]; float w = wf[(HH+c)*HH + h];
        acc[0]=fmaf(a.x,w,acc[0]); acc[1]=fmaf(a.y,w,acc[1]);
        acc[2]=fmaf(a.z,w,acc[2]); acc[3]=fmaf(a.w,w,acc[3]);
    }
    for (int c = 0; c < HH; ++c){
        float4 a = aL3[c]; float w = wf[(2*HH+c)*HH + h];
        acc[0]=fmaf(a.x,w,acc[0]); acc[1]=fmaf(a.y,w,acc[1]);
        acc[2]=fmaf(a.z,w,acc[2]); acc[3]=fmaf(a.w,w,acc[3]);
    }
    float4 xv = make_float4(fmaxf(acc[0],0.f), fmaxf(acc[1],0.f),
                            fmaxf(acc[2],0.f), fmaxf(acc[3],0.f));
    x[base] = xv.x; x[base+HH] = xv.y; x[base+2*HH] = xv.z; x[base+3*HH] = xv.w;
    xL[h] = xv;
    __syncthreads();

    float as[4]={0,0,0,0}, ar[4]={0,0,0,0};
    for (int c = 0; c < HH; ++c){
        float4 a = xL[c];
        float wsv = w1[c*HH+h], wrv = w1[(HH+c)*HH+h];
        as[0]=fmaf(a.x,wsv,as[0]); as[1]=fmaf(a.y,wsv,as[1]);
        as[2]=fmaf(a.z,wsv,as[2]); as[3]=fmaf(a.w,wsv,as[3]);
        ar[0]=fmaf(a.x,wrv,ar[0]); ar[1]=fmaf(a.y,wrv,ar[1]);
        ar[2]=fmaf(a.z,wrv,ar[2]); ar[3]=fmaf(a.w,wrv,ar[3]);
    }
    float b1v = b1[h];
    *reinterpret_cast<float4*>(hsT + ((size_t)b*HH + h)*SS + s0) =
        make_float4(as[0], as[1], as[2], as[3]);
    hr[base]      = ar[0] + b1v;
    hr[base+HH]   = ar[1] + b1v;
    hr[base+2*HH] = ar[2] + b1v;
    hr[base+3*HH] = ar[3] + b1v;
}

// ============ K3: edge logits + gumbel argmax -> adj (4-i tile) ===============
__global__ __launch_bounds__(128) void k_adj(
    const float* __restrict__ hsT, const float* __restrict__ hr,
    const float* __restrict__ w2, const float* __restrict__ b2,
    const float* __restrict__ gu, float* __restrict__ adj)
{
    int blk = blockIdx.x;          // (b, i-tile of 4)
    int b = blk >> 5; int i0 = (blk & 31) * 4;
    int j = threadIdx.x;
    __shared__ float4 hrT[HH];     // [h] = hr for i0..i0+3 at channel h
    __shared__ float w20L[HH], w21L[HH];
    {
        float v0 = hr[(size_t)(b*SS+i0+0)*HH + j];
        float v1 = hr[(size_t)(b*SS+i0+1)*HH + j];
        float v2 = hr[(size_t)(b*SS+i0+2)*HH + j];
        float v3 = hr[(size_t)(b*SS+i0+3)*HH + j];
        hrT[j] = make_float4(v0, v1, v2, v3);
        w20L[j] = w2[j*2 + 0];
        w21L[j] = w2[j*2 + 1];
    }
    __syncthreads();
    const float* hsb = hsT + (size_t)b*HH*SS;
    float d0[4] = {0,0,0,0}, d1[4] = {0,0,0,0};
    #pragma unroll 2
    for (int h = 0; h < HH; ++h){
        float hsv = hsb[h*SS + j];
        float4 hv = hrT[h];
        float wa = w20L[h], wb = w21L[h];
        float r0 = fmaxf(hsv + hv.x, 0.f);
        float r1 = fmaxf(hsv + hv.y, 0.f);
        float r2 = fmaxf(hsv + hv.z, 0.f);
        float r3 = fmaxf(hsv + hv.w, 0.f);
        d0[0]=fmaf(r0,wa,d0[0]); d1[0]=fmaf(r0,wb,d1[0]);
        d0[1]=fmaf(r1,wa,d0[1]); d1[1]=fmaf(r1,wb,d1[1]);
        d0[2]=fmaf(r2,wa,d0[2]); d1[2]=fmaf(r2,wb,d1[2]);
        d0[3]=fmaf(r3,wa,d0[3]); d1[3]=fmaf(r3,wb,d1[3]);
    }
    float b20 = b2[0], b21 = b2[1];
    #pragma unroll
    for (int ii = 0; ii < 4; ++ii){
        int i = i0 + ii;
        size_t e = (size_t)(b*SS+i)*SS + j;
        float2 uv = *reinterpret_cast<const float2*>(gu + e*2);
        float u0 = fminf(fmaxf(uv.x, 1e-6f), 0.999999f);
        float u1 = fminf(fmaxf(uv.y, 1e-6f), 0.999999f);
        float g0 = -logf(-logf(u0));
        float g1 = -logf(-logf(u1));
        float y0 = d0[ii] + b20 + g0;
        float y1 = d1[ii] + b21 + g1;
        adj[e] = (j > i && y0 >= y1) ? 1.f : 0.f;
    }
}

// ============ K4: fused deg + agg + lin + BN partials =========================
// block = (b, 4 output rows j0..j0+3); in is previous layer's pre-BN buffer,
// xn_eff = in*sc+sh applied on the fly.
__global__ __launch_bounds__(128) void k_gnn(
    const float* __restrict__ adj, const float* __restrict__ in,
    const float* __restrict__ scale_in, const float* __restrict__ shift_in, int aff,
    const float* __restrict__ wl, const float* __restrict__ bl,
    const float* __restrict__ wr,
    float* __restrict__ outb, float* __restrict__ part)
{
    int blk = blockIdx.x; int b = blk>>5; int j0 = (blk&31)*4; int h = threadIdx.x;
    __shared__ float4 adjL[SS];
    __shared__ float4 red[64];
    __shared__ float4 aggL[HH];
    __shared__ float4 xnL[HH];

    adjL[h] = *reinterpret_cast<const float4*>(adj + (size_t)(b*SS+h)*SS + j0);
    float sc = aff ? scale_in[h] : 1.f;
    float sh = aff ? shift_in[h] : 0.f;
    __syncthreads();
    // column degrees for j0..j0+3
    if (h < 64) red[h] = f4add(adjL[h], adjL[h+64]);
    __syncthreads();
    for (int off = 32; off; off >>= 1){
        if (h < off) red[h] = f4add(red[h], red[h+off]);
        __syncthreads();
    }
    float4 ds = red[0];
    float4 dv = make_float4(1.f/fmaxf(ds.x,1.f), 1.f/fmaxf(ds.y,1.f),
                            1.f/fmaxf(ds.z,1.f), 1.f/fmaxf(ds.w,1.f));
    // agg over i for channel h
    float a0=0.f, a1=0.f, a2=0.f, a3=0.f;
    const float* inb = in + (size_t)b*SS*HH + h;
    #pragma unroll 4
    for (int i = 0; i < SS; ++i){
        float xv = fmaf(inb[(size_t)i*HH], sc, sh);
        float4 av = adjL[i];
        a0=fmaf(av.x,xv,a0); a1=fmaf(av.y,xv,a1);
        a2=fmaf(av.z,xv,a2); a3=fmaf(av.w,xv,a3);
    }
    aggL[h] = make_float4(a0*dv.x, a1*dv.y, a2*dv.z, a3*dv.w);
    size_t base = (size_t)(b*SS+j0)*HH + h;
    xnL[h] = make_float4(fmaf(in[base],sc,sh), fmaf(in[base+HH],sc,sh),
                         fmaf(in[base+2*HH],sc,sh), fmaf(in[base+3*HH],sc,sh));
    __syncthreads();
    // lin: out = agg@wl + bl + xn_eff@wr
    float bv = bl[h];
    float acc[4] = {bv,bv,bv,bv};
    for (int c = 0; c < HH; ++c){
        float4 g = aggL[c]; float4 xv = xnL[c];
        float wlv = wl[c*HH+h], wrv = wr[c*HH+h];
        acc[0]=fmaf(g.x,wlv,acc[0]); acc[0]=fmaf(xv.x,wrv,acc[0]);
        acc[1]=fmaf(g.y,wlv,acc[1]); acc[1]=fmaf(xv.y,wrv,acc[1]);
        acc[2]=fmaf(g.z,wlv,acc[2]); acc[2]=fmaf(xv.z,wrv,acc[2]);
        acc[3]=fmaf(g.w,wlv,acc[3]); acc[3]=fmaf(xv.w,wrv,acc[3]);
    }
    outb[base]      = acc[0];
    outb[base+HH]   = acc[1];
    outb[base+2*HH] = acc[2];
    outb[base+3*HH] = acc[3];
    float psum = acc[0]+acc[1]+acc[2]+acc[3];
    float psq  = acc[0]*acc[0]+acc[1]*acc[1]+acc[2]*acc[2]+acc[3]*acc[3];
    part[h*1024 + blk]          = psum;
    part[131072 + h*1024 + blk] = psq;
}

// ============ K5: BN finalize (scale/shift) + capture normalized last row =====
__global__ __launch_bounds__(256) void k_bnfin(
    const float* __restrict__ part, const float* __restrict__ gamma,
    const float* __restrict__ beta, const float* __restrict__ outb,
    float* __restrict__ scale, float* __restrict__ shift, float* __restrict__ ol)
{
    int h = blockIdx.x; int t = threadIdx.x;
    float s1 = 0.f, s2 = 0.f;
    for (int i = t; i < 1024; i += 256){
        s1 += part[h*1024 + i];
        s2 += part[131072 + h*1024 + i];
    }
    __shared__ float r1[256], r2[256];
    __shared__ float sc_sh[2];
    r1[t] = s1; r2[t] = s2;
    __syncthreads();
    for (int off = 128; off; off >>= 1){
        if (t < off){ r1[t] += r1[t+off]; r2[t] += r2[t+off]; }
        __syncthreads();
    }
    if (t == 0){
        float m = r1[0] * (1.f/4096.f);
        float v = r2[0] * (1.f/4096.f) - m*m;
        v = fmaxf(v, 0.f);
        float sc = gamma[h] / sqrtf(v + 1e-5f);
        float sh = beta[h] - m*sc;
        scale[h] = sc; shift[h] = sh;
        sc_sh[0] = sc; sc_sh[1] = sh;
    }
    __syncthreads();
    if (t < BB){
        float val = outb[((size_t)t*SS + SS-1)*HH + h];
        ol[t*HH + h] = fmaf(val, sc_sh[0], sc_sh[1]);
    }
}

// ============ K6: head (gate -> we -> wo) =====================================
__global__ __launch_bounds__(128) void k_head(
    const float* __restrict__ ol, const float* __restrict__ wg,
    const float* __restrict__ bg, const float* __restrict__ we,
    const float* __restrict__ be, const float* __restrict__ wo,
    const float* __restrict__ bo, float* __restrict__ out)
{
    int b = blockIdx.x; int t = threadIdx.x;
    __shared__ float xw[HH];
    float a = bg[0];
    #pragma unroll
    for (int l = 0; l < 3; ++l) a = fmaf(ol[(l*BB + b)*HH + t], wg[l], a);
    xw[t] = fmaxf(a, 0.f);
    __syncthreads();
    if (t < 64){
        float acc = be[t];
        for (int h = 0; h < HH; ++h) acc = fmaf(xw[h], we[h*64 + t], acc);
        float h2 = fmaxf(acc, 0.f);
        float r = h2 * wo[t];
        #pragma unroll
        for (int off = 32; off; off >>= 1) r += __shfl_down(r, off, 64);
        if (t == 0) out[b] = r + bo[0];
    }
}

// ==============================================================================
extern "C" void kernel_launch(void* const* d_in, const int* in_sizes, int n_in,
                              void* d_out, int out_size, void* d_ws, size_t ws_size,
                              hipStream_t stream)
{
    const float* data = (const float*)d_in[0];
    const float* gu   = (const float*)d_in[1];
    const float* w11  = (const float*)d_in[2];
    const float* b11  = (const float*)d_in[3];
    const float* w12  = (const float*)d_in[4];
    const float* b12  = (const float*)d_in[5];
    const float* w21  = (const float*)d_in[6];
    const float* b21  = (const float*)d_in[7];
    const float* w22  = (const float*)d_in[8];
    const float* b22  = (const float*)d_in[9];
    const float* w31  = (const float*)d_in[10];
    const float* b31  = (const float*)d_in[11];
    const float* wf   = (const float*)d_in[12];
    const float* bf   = (const float*)d_in[13];
    const float* w1   = (const float*)d_in[14];
    const float* b1   = (const float*)d_in[15];
    const float* w2   = (const float*)d_in[16];
    const float* b2   = (const float*)d_in[17];
    const float* wl   = (const float*)d_in[18];
    const float* bl   = (const float*)d_in[19];
    const float* wr   = (const float*)d_in[20];
    const float* gamma= (const float*)d_in[21];
    const float* beta = (const float*)d_in[22];
    const float* wg   = (const float*)d_in[23];
    const float* bg   = (const float*)d_in[24];
    const float* we   = (const float*)d_in[25];
    const float* be   = (const float*)d_in[26];
    const float* wo   = (const float*)d_in[27];
    const float* bo   = (const float*)d_in[28];
    float* out = (float*)d_out;

    float* ws = (float*)d_ws;
    float* P = ws;                       // x1 -> hr
    float* Q = ws + (size_t)NBSH;        // x2 -> adj (persists through gnn loop)
    float* R = ws + (size_t)2*NBSH;      // t3 -> x -> out1
    float* S = ws + (size_t)3*NBSH;      // hsT -> out0 -> out2
    float* G = ws + (size_t)4*NBSH;      // wT3|wT5 (front), then BN partials
    float* wT3   = G;                    // 3*128*128
    float* wT5   = G + 49152;            // 5*128*128
    float* scale = G + 262144 + BB*SS;   // 3*128
    float* shift = scale + 3*HH;         // 3*128
    float* OL    = shift + 3*HH;         // 3*32*128

    k_prep<<<256, 128, 0, stream>>>(w12, w22, wT3, wT5);
    k_front<<<2048, 128, 0, stream>>>(data, w11,b11, w21,b21, w31,b31,
                                      wT3, b12, wT5, b22, P, Q, R);
    k_fuse_hs<<<1024, 128, 0, stream>>>(P, Q, R, wf, bf, w1, b1, R, S, P);
    k_adj<<<1024, 128, 0, stream>>>(S, P, w2, b2, gu, Q);

    const float* inl[3] = {R, S, R};
    float* outl[3]      = {S, R, S};
    for (int l = 0; l < 3; ++l){
        int aff = (l > 0);
        const float* sc = scale + (l>0 ? (l-1)*HH : 0);
        const float* sh = shift + (l>0 ? (l-1)*HH : 0);
        k_gnn<<<1024, 128, 0, stream>>>(Q, inl[l], sc, sh, aff,
            wl + (size_t)l*HH*HH, bl + (size_t)l*HH, wr + (size_t)l*HH*HH,
            outl[l], G);
        k_bnfin<<<HH, 256, 0, stream>>>(G, gamma + (size_t)l*HH, beta + (size_t)l*HH,
            outl[l], scale + l*HH, shift + l*HH, OL + (size_t)l*BB*HH);
    }
    k_head<<<BB, 128, 0, stream>>>(OL, wg, bg, we, be, wo, bo, out);
}